// Round 4
// baseline (411.994 us; speedup 1.0000x reference)
//
#include <hip/hip_runtime.h>
#include <hip/hip_bf16.h>
#include <cstdint>

#define B_  4
#define LQ_ 2048
#define LK_ 2048
#define D_  1024
#define H_  16
#define HD_ 64

typedef __attribute__((ext_vector_type(8))) short bf16x8;   // 8 bf16 in 4 VGPRs
typedef __attribute__((ext_vector_type(4))) float f32x4;    // MFMA C/D

#if defined(__has_builtin)
#if __has_builtin(__builtin_amdgcn_exp2f)
#define EXP2F(x) __builtin_amdgcn_exp2f(x)
#else
#define EXP2F(x) exp2f(x)
#endif
#else
#define EXP2F(x) exp2f(x)
#endif

__device__ __forceinline__ unsigned short f2b(float f) {   // RNE
    union { float f; unsigned u; } v; v.f = f;
    unsigned u = v.u;
    unsigned r = (u + 0x7fffu + ((u >> 16) & 1u)) >> 16;
    return (unsigned short)r;
}

// async global->LDS, 16B per lane. LDS dest semantics: wave-uniform base + lane*16.
__device__ __forceinline__ void gl_lds16(const unsigned short* g, unsigned short* l) {
    __builtin_amdgcn_global_load_lds(
        (const __attribute__((address_space(1))) unsigned int*)(g),
        (__attribute__((address_space(3))) unsigned int*)(l),
        16, 0, 0);
}

// ---------------------------------------------------------------------------
// fp32 -> bf16 conversion (optionally scaled). 8 elems/thread, grid-stride.
// ---------------------------------------------------------------------------
__global__ void cvt_bf16(const float* __restrict__ in,
                         unsigned short* __restrict__ out, int n, float scale) {
    int i = (blockIdx.x * blockDim.x + threadIdx.x) * 8;
    int stride = gridDim.x * blockDim.x * 8;
    for (; i < n; i += stride) {
        float4 a = *(const float4*)(in + i);
        float4 b = *(const float4*)(in + i + 4);
        bf16x8 v;
        v[0] = (short)f2b(a.x * scale); v[1] = (short)f2b(a.y * scale);
        v[2] = (short)f2b(a.z * scale); v[3] = (short)f2b(a.w * scale);
        v[4] = (short)f2b(b.x * scale); v[5] = (short)f2b(b.y * scale);
        v[6] = (short)f2b(b.z * scale); v[7] = (short)f2b(b.w * scale);
        *(bf16x8*)(out + i) = v;
    }
}

// ---------------------------------------------------------------------------
// Projection GEMM (bf16 in/out): Y[m][n] = sum_k X[m][k]*W[n][k] + bs*bias[n]
// M=8192 N=1024 K=1024. Block 256 (4 waves), tile 128m x 64n, BK=32.
// LDS is fragment-ordered: frag fa holds A[16*fa+l15][quad*8+j] at lane*16B.
// Staged with global_load_lds (async, 16B). Conflict-free ds_read_b128.
// ---------------------------------------------------------------------------
__global__ __launch_bounds__(256) void proj_gemm(
    const unsigned short* __restrict__ X,
    const unsigned short* __restrict__ W,
    const float* __restrict__ bias, float bscale,
    unsigned short* __restrict__ Y)
{
    __shared__ unsigned short As[8 * 512];   // 8 frags x 1KB  (128 rows x 32 k)
    __shared__ unsigned short Bs[4 * 512];   // 4 frags        (64 rows x 32 k)

    const int tid  = threadIdx.x;
    const int lane = tid & 63;
    const int w    = tid >> 6;
    const int wm   = w & 1, wn = w >> 1;       // wave tile: 64m x 32n
    const int m0   = blockIdx.y * 128;
    const int n0   = blockIdx.x * 64;
    const int l15  = lane & 15, quad = lane >> 4;

    f32x4 acc[4][2] = {};

    // lane-constant staging addresses
    const unsigned short* gA0 = X + (size_t)(m0 + (w * 2)     * 16 + l15) * 1024 + quad * 8;
    const unsigned short* gA1 = X + (size_t)(m0 + (w * 2 + 1) * 16 + l15) * 1024 + quad * 8;
    const unsigned short* gB0 = W + (size_t)(n0 + w * 16 + l15) * 1024 + quad * 8;
    unsigned short* lA0 = &As[(w * 2)     * 512 + lane * 8];
    unsigned short* lA1 = &As[(w * 2 + 1) * 512 + lane * 8];
    unsigned short* lB0 = &Bs[w * 512 + lane * 8];
    const unsigned short* frA = &As[(wm * 4) * 512 + lane * 8];   // + mt*512
    const unsigned short* frB = &Bs[(wn * 2) * 512 + lane * 8];   // + nt*512

    for (int k0 = 0; k0 < 1024; k0 += 32) {
        __syncthreads();
        gl_lds16(gA0 + k0, lA0);
        gl_lds16(gA1 + k0, lA1);
        gl_lds16(gB0 + k0, lB0);
        __syncthreads();

        bf16x8 af[4], bf[2];
        #pragma unroll
        for (int mt = 0; mt < 4; ++mt) af[mt] = *(const bf16x8*)(frA + mt * 512);
        #pragma unroll
        for (int nt = 0; nt < 2; ++nt) bf[nt] = *(const bf16x8*)(frB + nt * 512);

        #pragma unroll
        for (int mt = 0; mt < 4; ++mt)
            #pragma unroll
            for (int nt = 0; nt < 2; ++nt)
                acc[mt][nt] = __builtin_amdgcn_mfma_f32_16x16x32_bf16(
                    af[mt], bf[nt], acc[mt][nt], 0, 0, 0);
    }

    float bv[2];
    #pragma unroll
    for (int nt = 0; nt < 2; ++nt)
        bv[nt] = bias[n0 + wn * 32 + nt * 16 + l15] * bscale;

    #pragma unroll
    for (int mt = 0; mt < 4; ++mt) {
        #pragma unroll
        for (int r = 0; r < 4; ++r) {
            int row = m0 + wm * 64 + mt * 16 + quad * 4 + r;      // C/D: row = quad*4+reg
            unsigned short* yp = Y + (size_t)row * 1024 + n0 + wn * 32;
            #pragma unroll
            for (int nt = 0; nt < 2; ++nt)
                yp[nt * 16 + l15] = f2b(acc[mt][nt][r] + bv[nt]); // col = lane&15
        }
    }
}

// ---------------------------------------------------------------------------
// V transpose: Vb[b*2048+tok][h*64+d] -> Vt[((b*16+h)*64+d)][tok]
// ---------------------------------------------------------------------------
__global__ __launch_bounds__(256) void transpose_v(
    const unsigned short* __restrict__ Vb, unsigned short* __restrict__ Vt)
{
    __shared__ unsigned short L[64 * 72];
    const int t0 = blockIdx.x * 64, h = blockIdx.y, b = blockIdx.z;
    const int rr = threadIdx.x >> 3;
    const int cc = (threadIdx.x & 7) * 8;

    #pragma unroll
    for (int p = 0; p < 2; ++p) {
        int r = rr + p * 32;
        *(bf16x8*)(&L[r * 72 + cc]) =
            *(const bf16x8*)(Vb + (size_t)(b * 2048 + t0 + r) * 1024 + h * 64 + cc);
    }
    __syncthreads();
    #pragma unroll
    for (int p = 0; p < 2; ++p) {
        int d = rr + p * 32;
        bf16x8 v;
        #pragma unroll
        for (int j = 0; j < 8; ++j)
            v[j] = (short)L[(cc + j) * 72 + d];
        *(bf16x8*)(Vt + ((size_t)(b * 16 + h) * 64 + d) * 2048 + t0 + cc) = v;
    }
}

// ---------------------------------------------------------------------------
// Flash attention v3. Grid (16 qtiles, 16 heads, 4 b), block 256 (4 waves).
// 128 queries/block = 32/wave (2 halves of 16). 64-key tiles.
// No-max softmax: Q pre-scaled by 0.125*log2e, p = exp2(s), unnormalized
// accumulation, single normalization at end. Fragment-ordered LDS: every
// ds access is base + lane*16B + imm (conflict-free). Async staging.
// ---------------------------------------------------------------------------
__global__ __launch_bounds__(256) void attn_kernel(
    const unsigned short* __restrict__ Q,
    const unsigned short* __restrict__ Kp,
    const unsigned short* __restrict__ Vt,
    float* __restrict__ Out)
{
    __shared__ unsigned short Ks[8 * 512];    // frag (t*2+dblk): K[16t+l15][dblk*32+quad*8+j]
    __shared__ unsigned short Vs[8 * 512];    // frag (nt*2+hb):  V^T[nt*16+l15][hb*32+quad*8+j]
    __shared__ unsigned short Ps[8 * 1024];   // region (w*2+half): P frag-ordered

    const int tid  = threadIdx.x;
    const int lane = tid & 63;
    const int w    = tid >> 6;
    const int l15  = lane & 15, quad = lane >> 4;
    const int b = blockIdx.z, h = blockIdx.y, qt = blockIdx.x;

    // Q fragments for 2 query halves (scale folded into Wq/bq upstream)
    bf16x8 qf[2][2];
    #pragma unroll
    for (int half = 0; half < 2; ++half) {
        const unsigned short* qptr =
            Q + (size_t)(b * LQ_ + qt * 128 + w * 32 + half * 16 + l15) * 1024 + h * 64;
        qf[half][0] = *(const bf16x8*)(qptr + quad * 8);
        qf[half][1] = *(const bf16x8*)(qptr + 32 + quad * 8);
    }

    f32x4 oacc[2][4] = {};
    f32x4 psacc[2]   = {};

    const unsigned short* Kbase = Kp + (size_t)b * LK_ * 1024 + h * 64;
    const unsigned short* Vbase = Vt + (size_t)(b * 16 + h) * 64 * 2048;

    // lane-constant staging addresses (wave w stages frags 2w, 2w+1)
    const unsigned short* gK0 = Kbase + (size_t)(w * 16 + l15) * 1024 + 0  + quad * 8;
    const unsigned short* gK1 = Kbase + (size_t)(w * 16 + l15) * 1024 + 32 + quad * 8;
    const unsigned short* gV0 = Vbase + (size_t)(w * 16 + l15) * 2048 + 0  + quad * 8;
    const unsigned short* gV1 = Vbase + (size_t)(w * 16 + l15) * 2048 + 32 + quad * 8;
    unsigned short* lK0 = &Ks[(w * 2)     * 512 + lane * 8];
    unsigned short* lK1 = &Ks[(w * 2 + 1) * 512 + lane * 8];
    unsigned short* lV0 = &Vs[(w * 2)     * 512 + lane * 8];
    unsigned short* lV1 = &Vs[(w * 2 + 1) * 512 + lane * 8];

    // P write base (lane-const) and read bases
    const int pws = (quad >> 1) * 128 + l15 * 8 + (quad & 1) * 4;
    unsigned short* Pw0 = &Ps[(w * 2)     * 1024 + pws];
    unsigned short* Pw1 = &Ps[(w * 2 + 1) * 1024 + pws];
    const unsigned short* Pr0 = &Ps[(w * 2)     * 1024 + lane * 8];
    const unsigned short* Pr1 = &Ps[(w * 2 + 1) * 1024 + lane * 8];
    const unsigned short* Kfr = &Ks[lane * 8];
    const unsigned short* Vfr = &Vs[lane * 8];

    for (int k0 = 0; k0 < LK_; k0 += 64) {
        __syncthreads();
        gl_lds16(gK0 + (size_t)k0 * 1024, lK0);
        gl_lds16(gK1 + (size_t)k0 * 1024, lK1);
        gl_lds16(gV0 + k0, lV0);
        gl_lds16(gV1 + k0, lV1);
        __syncthreads();

        // ---- QK^T (S^T: col=query=l15, row=key=quad*4+r, tile t) ----
        f32x4 st[2][4] = {};
        #pragma unroll
        for (int t = 0; t < 4; ++t) {
            #pragma unroll
            for (int dblk = 0; dblk < 2; ++dblk) {
                bf16x8 kf = *(const bf16x8*)(Kfr + (t * 2 + dblk) * 512);
                st[0][t] = __builtin_amdgcn_mfma_f32_16x16x32_bf16(kf, qf[0][dblk], st[0][t], 0, 0, 0);
                st[1][t] = __builtin_amdgcn_mfma_f32_16x16x32_bf16(kf, qf[1][dblk], st[1][t], 0, 0, 0);
            }
        }

        // ---- p = exp2(s); accumulate row-sums; pack (RHU) into Ps ----
        #pragma unroll
        for (int half = 0; half < 2; ++half) {
            unsigned short* pw = half ? Pw1 : Pw0;
            #pragma unroll
            for (int t = 0; t < 4; ++t) {
                f32x4 p;
                p[0] = EXP2F(st[half][t][0]);
                p[1] = EXP2F(st[half][t][1]);
                p[2] = EXP2F(st[half][t][2]);
                p[3] = EXP2F(st[half][t][3]);
                psacc[half] += p;
                unsigned u0 = __float_as_uint(p[0]) + 0x8000u;
                unsigned u1 = __float_as_uint(p[1]) + 0x8000u;
                unsigned u2 = __float_as_uint(p[2]) + 0x8000u;
                unsigned u3 = __float_as_uint(p[3]) + 0x8000u;
                uint2 pk;
                pk.x = (u0 >> 16) | (u1 & 0xffff0000u);
                pk.y = (u2 >> 16) | (u3 & 0xffff0000u);
                *(uint2*)(pw + t * 256) = pk;
            }
        }

        // ---- PV: O += P*V (A=P[q][k], B=V[k][d]) ----
        #pragma unroll
        for (int hb = 0; hb < 2; ++hb) {
            bf16x8 pf0 = *(const bf16x8*)(Pr0 + hb * 512);
            bf16x8 pf1 = *(const bf16x8*)(Pr1 + hb * 512);
            #pragma unroll
            for (int nt = 0; nt < 4; ++nt) {
                bf16x8 vf = *(const bf16x8*)(Vfr + (nt * 2 + hb) * 512);
                oacc[0][nt] = __builtin_amdgcn_mfma_f32_16x16x32_bf16(pf0, vf, oacc[0][nt], 0, 0, 0);
                oacc[1][nt] = __builtin_amdgcn_mfma_f32_16x16x32_bf16(pf1, vf, oacc[1][nt], 0, 0, 0);
            }
        }
    }

    // ---- normalize + store ----
    #pragma unroll
    for (int half = 0; half < 2; ++half) {
        float ps = psacc[half][0] + psacc[half][1] + psacc[half][2] + psacc[half][3];
        ps += __shfl_xor(ps, 16, 64);
        ps += __shfl_xor(ps, 32, 64);
        float invl = 1.0f / ps;
        float il[4];
        #pragma unroll
        for (int r = 0; r < 4; ++r) il[r] = __shfl(invl, quad * 4 + r, 64);

        #pragma unroll
        for (int nt = 0; nt < 4; ++nt) {
            #pragma unroll
            for (int r = 0; r < 4; ++r) {
                size_t orow = (size_t)(b * LQ_ + qt * 128 + w * 32 + half * 16 + quad * 4 + r);
                Out[orow * 1024 + h * 64 + nt * 16 + l15] = oacc[half][nt][r] * il[r];
            }
        }
    }
}

// ---------------------------------------------------------------------------
extern "C" void kernel_launch(void* const* d_in, const int* in_sizes, int n_in,
                              void* d_out, int out_size, void* d_ws, size_t ws_size,
                              hipStream_t stream) {
    const float* zt = (const float*)d_in[0];
    const float* ic = (const float*)d_in[1];
    const float* Wq = (const float*)d_in[2];
    const float* bq = (const float*)d_in[3];
    const float* Wk = (const float*)d_in[4];
    const float* bk = (const float*)d_in[5];
    const float* Wv = (const float*)d_in[6];
    const float* bv = (const float*)d_in[7];
    float* out = (float*)d_out;

    const size_t M8 = (size_t)8192 * 1024;
    const size_t M1 = (size_t)1024 * 1024;
    unsigned short* Qb  = (unsigned short*)d_ws;
    unsigned short* Kb  = Qb  + M8;
    unsigned short* Vb  = Kb  + M8;
    unsigned short* Xz  = Vb  + M8;
    unsigned short* Xi  = Xz  + M8;
    unsigned short* Wqb = Xi  + M8;
    unsigned short* Wkb = Wqb + M1;
    unsigned short* Wvb = Wkb + M1;
    unsigned short* Vtb = Xz;                // Xz dead after proj Q

    const float qscale = 0.125f * 1.44269504088896f;  // 1/sqrt(64) * log2(e)

    cvt_bf16<<<4096, 256, 0, stream>>>(zt, Xz, (int)M8, 1.0f);
    cvt_bf16<<<4096, 256, 0, stream>>>(ic, Xi, (int)M8, 1.0f);
    cvt_bf16<<<512,  256, 0, stream>>>(Wq, Wqb, (int)M1, qscale);
    cvt_bf16<<<512,  256, 0, stream>>>(Wk, Wkb, (int)M1, 1.0f);
    cvt_bf16<<<512,  256, 0, stream>>>(Wv, Wvb, (int)M1, 1.0f);

    dim3 gproj(16, 64);                      // N/64, M/128
    proj_gemm<<<gproj, 256, 0, stream>>>(Xz, Wqb, bq, qscale, Qb);
    proj_gemm<<<gproj, 256, 0, stream>>>(Xi, Wkb, bk, 1.0f, Kb);
    proj_gemm<<<gproj, 256, 0, stream>>>(Xi, Wvb, bv, 1.0f, Vb);

    dim3 gtr(32, 16, 4);
    transpose_v<<<gtr, 256, 0, stream>>>(Vb, Vtb);

    dim3 gattn(16, 16, 4);                   // LQ/128, H, B
    attn_kernel<<<gattn, 256, 0, stream>>>(Qb, Kb, Vtb, out);
}

// Round 5
// 367.318 us; speedup vs baseline: 1.1216x; 1.1216x over previous
//
#include <hip/hip_runtime.h>
#include <hip/hip_bf16.h>
#include <cstdint>

#define B_  4
#define LQ_ 2048
#define LK_ 2048
#define D_  1024
#define H_  16
#define HD_ 64

typedef __attribute__((ext_vector_type(8))) short bf16x8;   // 8 bf16 in 4 VGPRs
typedef __attribute__((ext_vector_type(4))) float f32x4;    // MFMA C/D

#if defined(__has_builtin)
#if __has_builtin(__builtin_amdgcn_exp2f)
#define EXP2F(x) __builtin_amdgcn_exp2f(x)
#else
#define EXP2F(x) exp2f(x)
#endif
#else
#define EXP2F(x) exp2f(x)
#endif

__device__ __forceinline__ unsigned short f2b(float f) {   // RNE
    union { float f; unsigned u; } v; v.f = f;
    unsigned u = v.u;
    unsigned r = (u + 0x7fffu + ((u >> 16) & 1u)) >> 16;
    return (unsigned short)r;
}

// async global->LDS, 16B per lane. LDS dest: wave-uniform base + lane*16.
__device__ __forceinline__ void gl_lds16(const unsigned short* g, unsigned short* l) {
    __builtin_amdgcn_global_load_lds(
        (const __attribute__((address_space(1))) unsigned int*)(g),
        (__attribute__((address_space(3))) unsigned int*)(l),
        16, 0, 0);
}

// ---------------------------------------------------------------------------
// fp32 -> bf16 conversion (optionally scaled). 8 elems/thread, grid-stride.
// ---------------------------------------------------------------------------
__global__ void cvt_bf16(const float* __restrict__ in,
                         unsigned short* __restrict__ out, int n, float scale) {
    int i = (blockIdx.x * blockDim.x + threadIdx.x) * 8;
    int stride = gridDim.x * blockDim.x * 8;
    for (; i < n; i += stride) {
        float4 a = *(const float4*)(in + i);
        float4 b = *(const float4*)(in + i + 4);
        bf16x8 v;
        v[0] = (short)f2b(a.x * scale); v[1] = (short)f2b(a.y * scale);
        v[2] = (short)f2b(a.z * scale); v[3] = (short)f2b(a.w * scale);
        v[4] = (short)f2b(b.x * scale); v[5] = (short)f2b(b.y * scale);
        v[6] = (short)f2b(b.z * scale); v[7] = (short)f2b(b.w * scale);
        *(bf16x8*)(out + i) = v;
    }
}

// ---------------------------------------------------------------------------
// Projection GEMM (bf16 in/out): Y[m][n] = sum_k X[m][k]*W[n][k] + bs*bias[n]
// M=8192 N=1024 K=1024. Block 256 (4 waves, 2x2), tile 128x128, BK=64.
// Fragment-ordered LDS: frag f=(rt*2+kblk) holds T[rt*16+l15][kblk*32+quad*8+j]
// at f*1KB + lane*16B. 8 gl_lds16/thread/step, 32 MFMA/wave/step.
// ---------------------------------------------------------------------------
__global__ __launch_bounds__(256) void proj_gemm(
    const unsigned short* __restrict__ X,
    const unsigned short* __restrict__ W,
    const float* __restrict__ bias, float bscale,
    unsigned short* __restrict__ Y)
{
    __shared__ unsigned short As[16 * 512];   // 16 KB
    __shared__ unsigned short Bs[16 * 512];   // 16 KB

    const int tid  = threadIdx.x;
    const int lane = tid & 63;
    const int w    = tid >> 6;
    const int wm   = w & 1, wn = w >> 1;       // wave tile 64x64
    const int m0   = blockIdx.y * 128;
    const int n0   = blockIdx.x * 128;
    const int l15  = lane & 15, quad = lane >> 4;

    f32x4 acc[4][4] = {};

    // staging: wave w stages A/B frags f in {2w,2w+1, 8+2w,8+2w+1}
    // call j: rt = w + (j>>1)*4, kblk = j&1
    const unsigned short* gA[4];
    const unsigned short* gB[4];
    unsigned short* lA[4];
    unsigned short* lB[4];
    #pragma unroll
    for (int j = 0; j < 4; ++j) {
        int rt = w + (j >> 1) * 4, kblk = j & 1;
        int f = rt * 2 + kblk;
        gA[j] = X + (size_t)(m0 + rt * 16 + l15) * 1024 + kblk * 32 + quad * 8;
        gB[j] = W + (size_t)(n0 + rt * 16 + l15) * 1024 + kblk * 32 + quad * 8;
        lA[j] = &As[f * 512 + lane * 8];
        lB[j] = &Bs[f * 512 + lane * 8];
    }
    const unsigned short* frA = &As[(wm * 4) * 1024 + lane * 8];  // + mt*1024 + kblk*512
    const unsigned short* frB = &Bs[(wn * 4) * 1024 + lane * 8];

    for (int k0 = 0; k0 < 1024; k0 += 64) {
        __syncthreads();
        #pragma unroll
        for (int j = 0; j < 4; ++j) {
            gl_lds16(gA[j] + k0, lA[j]);
            gl_lds16(gB[j] + k0, lB[j]);
        }
        __syncthreads();

        #pragma unroll
        for (int kblk = 0; kblk < 2; ++kblk) {
            bf16x8 af[4], bf[4];
            #pragma unroll
            for (int mt = 0; mt < 4; ++mt)
                af[mt] = *(const bf16x8*)(frA + mt * 1024 + kblk * 512);
            #pragma unroll
            for (int nt = 0; nt < 4; ++nt)
                bf[nt] = *(const bf16x8*)(frB + nt * 1024 + kblk * 512);
            #pragma unroll
            for (int mt = 0; mt < 4; ++mt)
                #pragma unroll
                for (int nt = 0; nt < 4; ++nt)
                    acc[mt][nt] = __builtin_amdgcn_mfma_f32_16x16x32_bf16(
                        af[mt], bf[nt], acc[mt][nt], 0, 0, 0);
        }
    }

    float bv[4];
    #pragma unroll
    for (int nt = 0; nt < 4; ++nt)
        bv[nt] = bias[n0 + wn * 64 + nt * 16 + l15] * bscale;

    #pragma unroll
    for (int mt = 0; mt < 4; ++mt) {
        #pragma unroll
        for (int r = 0; r < 4; ++r) {
            int row = m0 + wm * 64 + mt * 16 + quad * 4 + r;      // C/D: row = quad*4+reg
            unsigned short* yp = Y + (size_t)row * 1024 + n0 + wn * 64;
            #pragma unroll
            for (int nt = 0; nt < 4; ++nt)
                yp[nt * 16 + l15] = f2b(acc[mt][nt][r] + bv[nt]); // col = lane&15
        }
    }
}

// ---------------------------------------------------------------------------
// V transpose: Vb[b*2048+tok][h*64+d] -> Vt[((b*16+h)*64+d)][tok]
// ---------------------------------------------------------------------------
__global__ __launch_bounds__(256) void transpose_v(
    const unsigned short* __restrict__ Vb, unsigned short* __restrict__ Vt)
{
    __shared__ unsigned short L[64 * 72];
    const int t0 = blockIdx.x * 64, h = blockIdx.y, b = blockIdx.z;
    const int rr = threadIdx.x >> 3;
    const int cc = (threadIdx.x & 7) * 8;

    #pragma unroll
    for (int p = 0; p < 2; ++p) {
        int r = rr + p * 32;
        *(bf16x8*)(&L[r * 72 + cc]) =
            *(const bf16x8*)(Vb + (size_t)(b * 2048 + t0 + r) * 1024 + h * 64 + cc);
    }
    __syncthreads();
    #pragma unroll
    for (int p = 0; p < 2; ++p) {
        int d = rr + p * 32;
        bf16x8 v;
        #pragma unroll
        for (int j = 0; j < 8; ++j)
            v[j] = (short)L[(cc + j) * 72 + d];
        *(bf16x8*)(Vt + ((size_t)(b * 16 + h) * 64 + d) * 2048 + t0 + cc) = v;
    }
}

// ---------------------------------------------------------------------------
// Flash attention v4. Grid (16 qtiles, 16 heads, 4 b), block 256 (4 waves).
// 128 q/block (32/wave). 128-key staged tiles (2 barriers each), compute in
// two 64-key chunks reusing wave-private P region. No-max softmax (Q
// pre-scaled by 0.125*log2e), p=exp2(s), normalize once at end.
// ---------------------------------------------------------------------------
__global__ __launch_bounds__(256) void attn_kernel(
    const unsigned short* __restrict__ Q,
    const unsigned short* __restrict__ Kp,
    const unsigned short* __restrict__ Vt,
    float* __restrict__ Out)
{
    __shared__ unsigned short Ks[16 * 512];   // frag f=kt*2+dblk: K[kt*16+l15][dblk*32+quad*8+j]
    __shared__ unsigned short Vs[16 * 512];   // frag f=nt*4+hb:  V^T[nt*16+l15][hb*32+quad*8+j]
    __shared__ unsigned short Ps[8 * 1024];   // region (w*2+half): P[16q][64k] frag-ordered

    const int tid  = threadIdx.x;
    const int lane = tid & 63;
    const int w    = tid >> 6;
    const int l15  = lane & 15, quad = lane >> 4;
    const int b = blockIdx.z, h = blockIdx.y, qt = blockIdx.x;

    bf16x8 qf[2][2];
    #pragma unroll
    for (int half = 0; half < 2; ++half) {
        const unsigned short* qptr =
            Q + (size_t)(b * LQ_ + qt * 128 + w * 32 + half * 16 + l15) * 1024 + h * 64;
        qf[half][0] = *(const bf16x8*)(qptr + quad * 8);
        qf[half][1] = *(const bf16x8*)(qptr + 32 + quad * 8);
    }

    f32x4 oacc[2][4] = {};
    f32x4 psacc[2]   = {};

    const unsigned short* Kbase = Kp + (size_t)b * LK_ * 1024 + h * 64;
    const unsigned short* Vbase = Vt + (size_t)(b * 16 + h) * 64 * 2048;

    // staging: wave w stages K frags kt in {w, w+4} x dblk, V frags nt=w x hb 0..3
    const unsigned short* gK[4];
    unsigned short* lK[4];
    const unsigned short* gV[4];
    unsigned short* lV[4];
    #pragma unroll
    for (int j = 0; j < 4; ++j) {
        int kt = w + (j >> 1) * 4, dblk = j & 1;
        gK[j] = Kbase + (size_t)(kt * 16 + l15) * 1024 + dblk * 32 + quad * 8;
        lK[j] = &Ks[(kt * 2 + dblk) * 512 + lane * 8];
        gV[j] = Vbase + (size_t)(w * 16 + l15) * 2048 + j * 32 + quad * 8;
        lV[j] = &Vs[(w * 4 + j) * 512 + lane * 8];
    }

    // P write base (lane-const within wave) and read bases
    const int pws = (quad >> 1) * 128 + l15 * 8 + (quad & 1) * 4;
    unsigned short* Pw0 = &Ps[(w * 2)     * 1024 + pws];
    unsigned short* Pw1 = &Ps[(w * 2 + 1) * 1024 + pws];
    const unsigned short* Pr0 = &Ps[(w * 2)     * 1024 + lane * 8];
    const unsigned short* Pr1 = &Ps[(w * 2 + 1) * 1024 + lane * 8];
    const unsigned short* Kfr = &Ks[lane * 8];
    const unsigned short* Vfr = &Vs[lane * 8];

    for (int k0 = 0; k0 < LK_; k0 += 128) {
        __syncthreads();
        #pragma unroll
        for (int j = 0; j < 4; ++j) {
            gl_lds16(gK[j] + (size_t)k0 * 1024, lK[j]);
            gl_lds16(gV[j] + k0, lV[j]);
        }
        __syncthreads();

        #pragma unroll
        for (int cc = 0; cc < 2; ++cc) {          // two 64-key chunks
            // ---- QK^T (S^T: col=query=l15, row=key=quad*4+r within tile t) ----
            f32x4 st[2][4] = {};
            #pragma unroll
            for (int t = 0; t < 4; ++t) {
                #pragma unroll
                for (int dblk = 0; dblk < 2; ++dblk) {
                    bf16x8 kf = *(const bf16x8*)(Kfr + ((cc * 4 + t) * 2 + dblk) * 512);
                    st[0][t] = __builtin_amdgcn_mfma_f32_16x16x32_bf16(kf, qf[0][dblk], st[0][t], 0, 0, 0);
                    st[1][t] = __builtin_amdgcn_mfma_f32_16x16x32_bf16(kf, qf[1][dblk], st[1][t], 0, 0, 0);
                }
            }

            // ---- p = exp2(s); accumulate row-sums; pack (RHU) into Ps ----
            #pragma unroll
            for (int half = 0; half < 2; ++half) {
                unsigned short* pw = half ? Pw1 : Pw0;
                #pragma unroll
                for (int t = 0; t < 4; ++t) {
                    f32x4 p;
                    p[0] = EXP2F(st[half][t][0]);
                    p[1] = EXP2F(st[half][t][1]);
                    p[2] = EXP2F(st[half][t][2]);
                    p[3] = EXP2F(st[half][t][3]);
                    psacc[half] += p;
                    unsigned u0 = __float_as_uint(p[0]) + 0x8000u;
                    unsigned u1 = __float_as_uint(p[1]) + 0x8000u;
                    unsigned u2 = __float_as_uint(p[2]) + 0x8000u;
                    unsigned u3 = __float_as_uint(p[3]) + 0x8000u;
                    uint2 pk;
                    pk.x = (u0 >> 16) | (u1 & 0xffff0000u);
                    pk.y = (u2 >> 16) | (u3 & 0xffff0000u);
                    *(uint2*)(pw + t * 256) = pk;
                }
            }

            // ---- PV: O += P*V ----
            #pragma unroll
            for (int hbl = 0; hbl < 2; ++hbl) {
                bf16x8 pf0 = *(const bf16x8*)(Pr0 + hbl * 512);
                bf16x8 pf1 = *(const bf16x8*)(Pr1 + hbl * 512);
                int hb = cc * 2 + hbl;
                #pragma unroll
                for (int nt = 0; nt < 4; ++nt) {
                    bf16x8 vf = *(const bf16x8*)(Vfr + (nt * 4 + hb) * 512);
                    oacc[0][nt] = __builtin_amdgcn_mfma_f32_16x16x32_bf16(pf0, vf, oacc[0][nt], 0, 0, 0);
                    oacc[1][nt] = __builtin_amdgcn_mfma_f32_16x16x32_bf16(pf1, vf, oacc[1][nt], 0, 0, 0);
                }
            }
        }
    }

    // ---- normalize + store ----
    #pragma unroll
    for (int half = 0; half < 2; ++half) {
        float ps = psacc[half][0] + psacc[half][1] + psacc[half][2] + psacc[half][3];
        ps += __shfl_xor(ps, 16, 64);
        ps += __shfl_xor(ps, 32, 64);
        float invl = 1.0f / ps;
        float il[4];
        #pragma unroll
        for (int r = 0; r < 4; ++r) il[r] = __shfl(invl, quad * 4 + r, 64);

        #pragma unroll
        for (int nt = 0; nt < 4; ++nt) {
            #pragma unroll
            for (int r = 0; r < 4; ++r) {
                size_t orow = (size_t)(b * LQ_ + qt * 128 + w * 32 + half * 16 + quad * 4 + r);
                Out[orow * 1024 + h * 64 + nt * 16 + l15] = oacc[half][nt][r] * il[r];
            }
        }
    }
}

// ---------------------------------------------------------------------------
extern "C" void kernel_launch(void* const* d_in, const int* in_sizes, int n_in,
                              void* d_out, int out_size, void* d_ws, size_t ws_size,
                              hipStream_t stream) {
    const float* zt = (const float*)d_in[0];
    const float* ic = (const float*)d_in[1];
    const float* Wq = (const float*)d_in[2];
    const float* bq = (const float*)d_in[3];
    const float* Wk = (const float*)d_in[4];
    const float* bk = (const float*)d_in[5];
    const float* Wv = (const float*)d_in[6];
    const float* bv = (const float*)d_in[7];
    float* out = (float*)d_out;

    const size_t M8 = (size_t)8192 * 1024;
    const size_t M1 = (size_t)1024 * 1024;
    unsigned short* Qb  = (unsigned short*)d_ws;
    unsigned short* Kb  = Qb  + M8;
    unsigned short* Vb  = Kb  + M8;
    unsigned short* Xz  = Vb  + M8;
    unsigned short* Xi  = Xz  + M8;
    unsigned short* Wqb = Xi  + M8;
    unsigned short* Wkb = Wqb + M1;
    unsigned short* Wvb = Wkb + M1;
    unsigned short* Vtb = Xz;                // Xz dead after proj Q

    const float qscale = 0.125f * 1.44269504088896f;  // 1/sqrt(64) * log2(e)

    cvt_bf16<<<4096, 256, 0, stream>>>(zt, Xz, (int)M8, 1.0f);
    cvt_bf16<<<4096, 256, 0, stream>>>(ic, Xi, (int)M8, 1.0f);
    cvt_bf16<<<512,  256, 0, stream>>>(Wq, Wqb, (int)M1, qscale);
    cvt_bf16<<<512,  256, 0, stream>>>(Wk, Wkb, (int)M1, 1.0f);
    cvt_bf16<<<512,  256, 0, stream>>>(Wv, Wvb, (int)M1, 1.0f);

    dim3 gproj(8, 64);                       // N/128, M/128
    proj_gemm<<<gproj, 256, 0, stream>>>(Xz, Wqb, bq, qscale, Qb);
    proj_gemm<<<gproj, 256, 0, stream>>>(Xi, Wkb, bk, 1.0f, Kb);
    proj_gemm<<<gproj, 256, 0, stream>>>(Xi, Wvb, bv, 1.0f, Vb);

    dim3 gtr(32, 16, 4);
    transpose_v<<<gtr, 256, 0, stream>>>(Vb, Vtb);

    dim3 gattn(16, 16, 4);                   // LQ/128, H, B
    attn_kernel<<<gattn, 256, 0, stream>>>(Qb, Kb, Vtb, out);
}

// Round 6
// 355.419 us; speedup vs baseline: 1.1592x; 1.0335x over previous
//
#include <hip/hip_runtime.h>
#include <hip/hip_bf16.h>
#include <cstdint>

#define B_  4
#define LQ_ 2048
#define LK_ 2048
#define D_  1024
#define H_  16
#define HD_ 64

typedef __attribute__((ext_vector_type(8))) short bf16x8;   // 8 bf16 in 4 VGPRs
typedef __attribute__((ext_vector_type(4))) float f32x4;    // MFMA C/D

#if defined(__has_builtin)
#if __has_builtin(__builtin_amdgcn_exp2f)
#define EXP2F(x) __builtin_amdgcn_exp2f(x)
#else
#define EXP2F(x) exp2f(x)
#endif
#else
#define EXP2F(x) exp2f(x)
#endif

__device__ __forceinline__ unsigned short f2b(float f) {   // RNE
    union { float f; unsigned u; } v; v.f = f;
    unsigned u = v.u;
    unsigned r = (u + 0x7fffu + ((u >> 16) & 1u)) >> 16;
    return (unsigned short)r;
}

// async global->LDS, 16B per lane. LDS dest: wave-uniform base + lane*16.
__device__ __forceinline__ void gl_lds16(const unsigned short* g, unsigned short* l) {
    __builtin_amdgcn_global_load_lds(
        (const __attribute__((address_space(1))) unsigned int*)(g),
        (__attribute__((address_space(3))) unsigned int*)(l),
        16, 0, 0);
}

// ---------------------------------------------------------------------------
// Fused fp32->bf16 converts (2 big activations / 3 weights), blockIdx.y picks.
// ---------------------------------------------------------------------------
__global__ void cvt_x2(const float* __restrict__ a, unsigned short* __restrict__ oa,
                       const float* __restrict__ b, unsigned short* __restrict__ ob,
                       int n) {
    const float* in  = blockIdx.y ? b : a;
    unsigned short* out = blockIdx.y ? ob : oa;
    int i = (blockIdx.x * blockDim.x + threadIdx.x) * 8;
    int stride = gridDim.x * blockDim.x * 8;
    for (; i < n; i += stride) {
        float4 x = *(const float4*)(in + i);
        float4 y = *(const float4*)(in + i + 4);
        bf16x8 v;
        v[0] = (short)f2b(x.x); v[1] = (short)f2b(x.y);
        v[2] = (short)f2b(x.z); v[3] = (short)f2b(x.w);
        v[4] = (short)f2b(y.x); v[5] = (short)f2b(y.y);
        v[6] = (short)f2b(y.z); v[7] = (short)f2b(y.w);
        *(bf16x8*)(out + i) = v;
    }
}

__global__ void cvt_w3(const float* __restrict__ w0, unsigned short* __restrict__ o0, float s0,
                       const float* __restrict__ w1, unsigned short* __restrict__ o1,
                       const float* __restrict__ w2, unsigned short* __restrict__ o2,
                       int n) {
    const float* in; unsigned short* out; float s;
    if (blockIdx.y == 0)      { in = w0; out = o0; s = s0;   }
    else if (blockIdx.y == 1) { in = w1; out = o1; s = 1.0f; }
    else                      { in = w2; out = o2; s = 1.0f; }
    int i = (blockIdx.x * blockDim.x + threadIdx.x) * 8;
    int stride = gridDim.x * blockDim.x * 8;
    for (; i < n; i += stride) {
        float4 x = *(const float4*)(in + i);
        float4 y = *(const float4*)(in + i + 4);
        bf16x8 v;
        v[0] = (short)f2b(x.x * s); v[1] = (short)f2b(x.y * s);
        v[2] = (short)f2b(x.z * s); v[3] = (short)f2b(x.w * s);
        v[4] = (short)f2b(y.x * s); v[5] = (short)f2b(y.y * s);
        v[6] = (short)f2b(y.z * s); v[7] = (short)f2b(y.w * s);
        *(bf16x8*)(out + i) = v;
    }
}

// ---------------------------------------------------------------------------
// Fused QKV projection GEMM. Grid (24, 64): x = proj*8 + ntile.
// Y[m][n] = sum_k X[m][k]*W[n][k] + bs*bias[n], tile 128x128, BK=64,
// fragment-ordered LDS, async 16B staging, 32 MFMA/wave/step.
// ---------------------------------------------------------------------------
__global__ __launch_bounds__(256) void qkv_gemm(
    const unsigned short* __restrict__ Xq,  // bf16 zt
    const unsigned short* __restrict__ Xkv, // bf16 ic
    const unsigned short* __restrict__ Wqb, const unsigned short* __restrict__ Wkb,
    const unsigned short* __restrict__ Wvb,
    const float* __restrict__ bq, const float* __restrict__ bk,
    const float* __restrict__ bv, float qscale,
    unsigned short* __restrict__ Qb, unsigned short* __restrict__ Kb,
    unsigned short* __restrict__ Vb)
{
    __shared__ unsigned short As[16 * 512];   // 16 KB
    __shared__ unsigned short Bs[16 * 512];   // 16 KB

    const int proj = blockIdx.x >> 3;
    const int nt0  = blockIdx.x & 7;
    const unsigned short* X = (proj == 0) ? Xq : Xkv;
    const unsigned short* W = (proj == 0) ? Wqb : (proj == 1 ? Wkb : Wvb);
    const float* bias       = (proj == 0) ? bq  : (proj == 1 ? bk  : bv);
    unsigned short* Y       = (proj == 0) ? Qb  : (proj == 1 ? Kb  : Vb);
    const float bscale      = (proj == 0) ? qscale : 1.0f;

    const int tid  = threadIdx.x;
    const int lane = tid & 63;
    const int w    = tid >> 6;
    const int wm   = w & 1, wn = w >> 1;       // wave tile 64x64
    const int m0   = blockIdx.y * 128;
    const int n0   = nt0 * 128;
    const int l15  = lane & 15, quad = lane >> 4;

    f32x4 acc[4][4] = {};

    const unsigned short* gA[4];
    const unsigned short* gB[4];
    unsigned short* lA[4];
    unsigned short* lB[4];
    #pragma unroll
    for (int j = 0; j < 4; ++j) {
        int rt = w + (j >> 1) * 4, kblk = j & 1;
        int f = rt * 2 + kblk;
        gA[j] = X + (size_t)(m0 + rt * 16 + l15) * 1024 + kblk * 32 + quad * 8;
        gB[j] = W + (size_t)(n0 + rt * 16 + l15) * 1024 + kblk * 32 + quad * 8;
        lA[j] = &As[f * 512 + lane * 8];
        lB[j] = &Bs[f * 512 + lane * 8];
    }
    const unsigned short* frA = &As[(wm * 4) * 1024 + lane * 8];  // + mt*1024 + kblk*512
    const unsigned short* frB = &Bs[(wn * 4) * 1024 + lane * 8];

    for (int k0 = 0; k0 < 1024; k0 += 64) {
        __syncthreads();
        #pragma unroll
        for (int j = 0; j < 4; ++j) {
            gl_lds16(gA[j] + k0, lA[j]);
            gl_lds16(gB[j] + k0, lB[j]);
        }
        __syncthreads();

        #pragma unroll
        for (int kblk = 0; kblk < 2; ++kblk) {
            bf16x8 af[4], bf[4];
            #pragma unroll
            for (int mt = 0; mt < 4; ++mt)
                af[mt] = *(const bf16x8*)(frA + mt * 1024 + kblk * 512);
            #pragma unroll
            for (int nt = 0; nt < 4; ++nt)
                bf[nt] = *(const bf16x8*)(frB + nt * 1024 + kblk * 512);
            #pragma unroll
            for (int mt = 0; mt < 4; ++mt)
                #pragma unroll
                for (int nt = 0; nt < 4; ++nt)
                    acc[mt][nt] = __builtin_amdgcn_mfma_f32_16x16x32_bf16(
                        af[mt], bf[nt], acc[mt][nt], 0, 0, 0);
        }
    }

    float bvv[4];
    #pragma unroll
    for (int nt = 0; nt < 4; ++nt)
        bvv[nt] = bias[n0 + wn * 64 + nt * 16 + l15] * bscale;

    #pragma unroll
    for (int mt = 0; mt < 4; ++mt) {
        #pragma unroll
        for (int r = 0; r < 4; ++r) {
            int row = m0 + wm * 64 + mt * 16 + quad * 4 + r;      // C/D: row = quad*4+reg
            unsigned short* yp = Y + (size_t)row * 1024 + n0 + wn * 64;
            #pragma unroll
            for (int nt = 0; nt < 4; ++nt)
                yp[nt * 16 + l15] = f2b(acc[mt][nt][r] + bvv[nt]); // col = lane&15
        }
    }
}

// ---------------------------------------------------------------------------
// V transpose: Vb[b*2048+tok][h*64+d] -> Vt[((b*16+h)*64+d)][tok]
// ---------------------------------------------------------------------------
__global__ __launch_bounds__(256) void transpose_v(
    const unsigned short* __restrict__ Vb, unsigned short* __restrict__ Vt)
{
    __shared__ unsigned short L[64 * 72];
    const int t0 = blockIdx.x * 64, h = blockIdx.y, b = blockIdx.z;
    const int rr = threadIdx.x >> 3;
    const int cc = (threadIdx.x & 7) * 8;

    #pragma unroll
    for (int p = 0; p < 2; ++p) {
        int r = rr + p * 32;
        *(bf16x8*)(&L[r * 72 + cc]) =
            *(const bf16x8*)(Vb + (size_t)(b * 2048 + t0 + r) * 1024 + h * 64 + cc);
    }
    __syncthreads();
    #pragma unroll
    for (int p = 0; p < 2; ++p) {
        int d = rr + p * 32;
        bf16x8 v;
        #pragma unroll
        for (int j = 0; j < 8; ++j)
            v[j] = (short)L[(cc + j) * 72 + d];
        *(bf16x8*)(Vt + ((size_t)(b * 16 + h) * 64 + d) * 2048 + t0 + cc) = v;
    }
}

// ---------------------------------------------------------------------------
// Flash attention v5. Grid (16,16,4), block 256 (4 waves), 128 q/block.
// 128-key staged tiles; sequential query-halves reuse one 2KB P-region/wave
// (LDS 40KB -> 4 blocks/CU). No-max softmax, p=exp2(s). Row-sums via
// all-ones-B MFMA (row-aligned with oacc; no epilogue shuffles). P packed
// with v_perm (round-half-up).
// ---------------------------------------------------------------------------
__global__ __launch_bounds__(256) void attn_kernel(
    const unsigned short* __restrict__ Q,
    const unsigned short* __restrict__ Kp,
    const unsigned short* __restrict__ Vt,
    float* __restrict__ Out)
{
    __shared__ unsigned short Ks[16 * 512];   // frag f=kt*2+dblk: K[kt*16+l15][dblk*32+quad*8+j]
    __shared__ unsigned short Vs[16 * 512];   // frag f=nt*4+hb:  V^T[nt*16+l15][hb*32+quad*8+j]
    __shared__ unsigned short Ps[4][1024];    // per-wave P[16q][64k] frag-ordered

    const int tid  = threadIdx.x;
    const int lane = tid & 63;
    const int w    = tid >> 6;
    const int l15  = lane & 15, quad = lane >> 4;
    const int b = blockIdx.z, h = blockIdx.y, qt = blockIdx.x;

    bf16x8 qf[2][2];
    #pragma unroll
    for (int half = 0; half < 2; ++half) {
        const unsigned short* qptr =
            Q + (size_t)(b * LQ_ + qt * 128 + w * 32 + half * 16 + l15) * 1024 + h * 64;
        qf[half][0] = *(const bf16x8*)(qptr + quad * 8);
        qf[half][1] = *(const bf16x8*)(qptr + 32 + quad * 8);
    }

    bf16x8 ones;
    #pragma unroll
    for (int j = 0; j < 8; ++j) ones[j] = (short)0x3F80;   // bf16 1.0

    f32x4 oacc[2][4] = {};
    f32x4 lacc[2]    = {};    // row-sums (rows = q, same alignment as oacc)

    const unsigned short* Kbase = Kp + (size_t)b * LK_ * 1024 + h * 64;
    const unsigned short* Vbase = Vt + (size_t)(b * 16 + h) * 64 * 2048;

    const unsigned short* gK[4];
    unsigned short* lK[4];
    const unsigned short* gV[4];
    unsigned short* lV[4];
    #pragma unroll
    for (int j = 0; j < 4; ++j) {
        int kt = w + (j >> 1) * 4, dblk = j & 1;
        gK[j] = Kbase + (size_t)(kt * 16 + l15) * 1024 + dblk * 32 + quad * 8;
        lK[j] = &Ks[(kt * 2 + dblk) * 512 + lane * 8];
        gV[j] = Vbase + (size_t)(w * 16 + l15) * 2048 + j * 32 + quad * 8;
        lV[j] = &Vs[(w * 4 + j) * 512 + lane * 8];
    }

    // P region addressing (wave-private): element (q,k) at (k>>3)*128 + q*8 + (k&7)
    const int pws = (quad >> 1) * 128 + l15 * 8 + (quad & 1) * 4;
    unsigned short* Pw = &Ps[w][pws];
    const unsigned short* Pr = &Ps[w][lane * 8];
    const unsigned short* Kfr = &Ks[lane * 8];
    const unsigned short* Vfr = &Vs[lane * 8];

    for (int k0 = 0; k0 < LK_; k0 += 128) {
        __syncthreads();
        #pragma unroll
        for (int j = 0; j < 4; ++j) {
            gl_lds16(gK[j] + (size_t)k0 * 1024, lK[j]);
            gl_lds16(gV[j] + k0, lV[j]);
        }
        __syncthreads();

        #pragma unroll
        for (int cc = 0; cc < 2; ++cc) {          // two 64-key chunks
            #pragma unroll
            for (int half = 0; half < 2; ++half) {
                // ---- QK^T (S^T: col=query=l15, row=key=quad*4+r, tile t) ----
                f32x4 st[4] = {};
                #pragma unroll
                for (int t = 0; t < 4; ++t)
                    #pragma unroll
                    for (int dblk = 0; dblk < 2; ++dblk) {
                        bf16x8 kf = *(const bf16x8*)(Kfr + ((cc * 4 + t) * 2 + dblk) * 512);
                        st[t] = __builtin_amdgcn_mfma_f32_16x16x32_bf16(
                            kf, qf[half][dblk], st[t], 0, 0, 0);
                    }

                // ---- p = exp2(s); pack (RHU) into P region ----
                #pragma unroll
                for (int t = 0; t < 4; ++t) {
                    unsigned u0 = __float_as_uint(EXP2F(st[t][0])) + 0x8000u;
                    unsigned u1 = __float_as_uint(EXP2F(st[t][1])) + 0x8000u;
                    unsigned u2 = __float_as_uint(EXP2F(st[t][2])) + 0x8000u;
                    unsigned u3 = __float_as_uint(EXP2F(st[t][3])) + 0x8000u;
                    uint2 pk;
                    pk.x = __builtin_amdgcn_perm(u1, u0, 0x07060302);
                    pk.y = __builtin_amdgcn_perm(u3, u2, 0x07060302);
                    *(uint2*)(Pw + t * 256) = pk;
                }

                // ---- PV + ones row-sum ----
                #pragma unroll
                for (int hbl = 0; hbl < 2; ++hbl) {
                    bf16x8 pf = *(const bf16x8*)(Pr + hbl * 512);
                    lacc[half] = __builtin_amdgcn_mfma_f32_16x16x32_bf16(
                        pf, ones, lacc[half], 0, 0, 0);
                    int hb = cc * 2 + hbl;
                    #pragma unroll
                    for (int nt = 0; nt < 4; ++nt) {
                        bf16x8 vf = *(const bf16x8*)(Vfr + (nt * 4 + hb) * 512);
                        oacc[half][nt] = __builtin_amdgcn_mfma_f32_16x16x32_bf16(
                            pf, vf, oacc[half][nt], 0, 0, 0);
                    }
                }
            }
        }
    }

    // ---- normalize + store (lacc rows already aligned with oacc rows) ----
    #pragma unroll
    for (int half = 0; half < 2; ++half) {
        float il[4];
        #pragma unroll
        for (int r = 0; r < 4; ++r) il[r] = 1.0f / lacc[half][r];
        #pragma unroll
        for (int nt = 0; nt < 4; ++nt) {
            #pragma unroll
            for (int r = 0; r < 4; ++r) {
                size_t orow = (size_t)(b * LQ_ + qt * 128 + w * 32 + half * 16 + quad * 4 + r);
                Out[orow * 1024 + h * 64 + nt * 16 + l15] = oacc[half][nt][r] * il[r];
            }
        }
    }
}

// ---------------------------------------------------------------------------
extern "C" void kernel_launch(void* const* d_in, const int* in_sizes, int n_in,
                              void* d_out, int out_size, void* d_ws, size_t ws_size,
                              hipStream_t stream) {
    const float* zt = (const float*)d_in[0];
    const float* ic = (const float*)d_in[1];
    const float* Wq = (const float*)d_in[2];
    const float* bq = (const float*)d_in[3];
    const float* Wk = (const float*)d_in[4];
    const float* bk = (const float*)d_in[5];
    const float* Wv = (const float*)d_in[6];
    const float* bv = (const float*)d_in[7];
    float* out = (float*)d_out;

    const size_t M8 = (size_t)8192 * 1024;
    const size_t M1 = (size_t)1024 * 1024;
    unsigned short* Qb  = (unsigned short*)d_ws;
    unsigned short* Kb  = Qb  + M8;
    unsigned short* Vb  = Kb  + M8;
    unsigned short* Xz  = Vb  + M8;
    unsigned short* Xi  = Xz  + M8;
    unsigned short* Wqb = Xi  + M8;
    unsigned short* Wkb = Wqb + M1;
    unsigned short* Wvb = Wkb + M1;
    unsigned short* Vtb = Xz;                // Xz dead after qkv_gemm

    const float qscale = 0.125f * 1.44269504088896f;  // 1/sqrt(64) * log2(e)

    dim3 gcx(4096, 2);
    cvt_x2<<<gcx, 256, 0, stream>>>(zt, Xz, ic, Xi, (int)M8);
    dim3 gcw(512, 3);
    cvt_w3<<<gcw, 256, 0, stream>>>(Wq, Wqb, qscale, Wk, Wkb, Wv, Wvb, (int)M1);

    dim3 gproj(24, 64);                      // (proj*8 + ntile), M/128
    qkv_gemm<<<gproj, 256, 0, stream>>>(Xz, Xi, Wqb, Wkb, Wvb,
                                        bq, bk, bv, qscale, Qb, Kb, Vb);

    dim3 gtr(32, 16, 4);
    transpose_v<<<gtr, 256, 0, stream>>>(Vb, Vtb);

    dim3 gattn(16, 16, 4);                   // LQ/128, H, B
    attn_kernel<<<gattn, 256, 0, stream>>>(Qb, Kb, Vtb, out);
}

// Round 7
// 318.055 us; speedup vs baseline: 1.2954x; 1.1175x over previous
//
#include <hip/hip_runtime.h>
#include <hip/hip_bf16.h>
#include <cstdint>

#define B_  4
#define LQ_ 2048
#define LK_ 2048
#define D_  1024
#define H_  16
#define HD_ 64

typedef __attribute__((ext_vector_type(8))) short bf16x8;   // 8 bf16 in 4 VGPRs
typedef __attribute__((ext_vector_type(4))) float f32x4;    // MFMA C/D

#if defined(__has_builtin)
#if __has_builtin(__builtin_amdgcn_exp2f)
#define EXP2F(x) __builtin_amdgcn_exp2f(x)
#else
#define EXP2F(x) exp2f(x)
#endif
#else
#define EXP2F(x) exp2f(x)
#endif

__device__ __forceinline__ unsigned short f2b(float f) {   // RNE
    union { float f; unsigned u; } v; v.f = f;
    unsigned u = v.u;
    unsigned r = (u + 0x7fffu + ((u >> 16) & 1u)) >> 16;
    return (unsigned short)r;
}

// async global->LDS, 16B per lane. LDS dest: wave-uniform base + lane*16.
__device__ __forceinline__ void gl_lds16(const unsigned short* g, unsigned short* l) {
    __builtin_amdgcn_global_load_lds(
        (const __attribute__((address_space(1))) unsigned int*)(g),
        (__attribute__((address_space(3))) unsigned int*)(l),
        16, 0, 0);
}

// ---------------------------------------------------------------------------
// Fused fp32->bf16 for all 5 tensors; blockIdx.y selects. Wq scaled by s0.
// ---------------------------------------------------------------------------
__global__ void cvt_all(const float* __restrict__ a0, unsigned short* __restrict__ d0,
                        const float* __restrict__ a1, unsigned short* __restrict__ d1,
                        const float* __restrict__ w0, unsigned short* __restrict__ e0, float s0,
                        const float* __restrict__ w1, unsigned short* __restrict__ e1,
                        const float* __restrict__ w2, unsigned short* __restrict__ e2,
                        int nact, int nw) {
    const float* in; unsigned short* out; float s = 1.0f; int n;
    switch (blockIdx.y) {
        case 0: in = a0; out = d0; n = nact; break;
        case 1: in = a1; out = d1; n = nact; break;
        case 2: in = w0; out = e0; n = nw; s = s0; break;
        case 3: in = w1; out = e1; n = nw; break;
        default: in = w2; out = e2; n = nw; break;
    }
    int i = (blockIdx.x * blockDim.x + threadIdx.x) * 8;
    int stride = gridDim.x * blockDim.x * 8;
    for (; i < n; i += stride) {
        float4 x = *(const float4*)(in + i);
        float4 y = *(const float4*)(in + i + 4);
        bf16x8 v;
        v[0] = (short)f2b(x.x * s); v[1] = (short)f2b(x.y * s);
        v[2] = (short)f2b(x.z * s); v[3] = (short)f2b(x.w * s);
        v[4] = (short)f2b(y.x * s); v[5] = (short)f2b(y.y * s);
        v[6] = (short)f2b(y.z * s); v[7] = (short)f2b(y.w * s);
        *(bf16x8*)(out + i) = v;
    }
}

// ---------------------------------------------------------------------------
// Fused QKV projection GEMM. Grid (24, 64): x = proj*8 + ntile.
// Y[m][n] = sum_k X[m][k]*W[n][k] + bs*bias[n], tile 128x128, BK=64,
// fragment-ordered LDS, async 16B staging, 32 MFMA/wave/step.
// ---------------------------------------------------------------------------
__global__ __launch_bounds__(256) void qkv_gemm(
    const unsigned short* __restrict__ Xq,
    const unsigned short* __restrict__ Xkv,
    const unsigned short* __restrict__ Wqb, const unsigned short* __restrict__ Wkb,
    const unsigned short* __restrict__ Wvb,
    const float* __restrict__ bq, const float* __restrict__ bk,
    const float* __restrict__ bv, float qscale,
    unsigned short* __restrict__ Qb, unsigned short* __restrict__ Kb,
    unsigned short* __restrict__ Vb)
{
    __shared__ unsigned short As[16 * 512];
    __shared__ unsigned short Bs[16 * 512];

    const int proj = blockIdx.x >> 3;
    const int nt0  = blockIdx.x & 7;
    const unsigned short* X = (proj == 0) ? Xq : Xkv;
    const unsigned short* W = (proj == 0) ? Wqb : (proj == 1 ? Wkb : Wvb);
    const float* bias       = (proj == 0) ? bq  : (proj == 1 ? bk  : bv);
    unsigned short* Y       = (proj == 0) ? Qb  : (proj == 1 ? Kb  : Vb);
    const float bscale      = (proj == 0) ? qscale : 1.0f;

    const int tid  = threadIdx.x;
    const int lane = tid & 63;
    const int w    = tid >> 6;
    const int wm   = w & 1, wn = w >> 1;
    const int m0   = blockIdx.y * 128;
    const int n0   = nt0 * 128;
    const int l15  = lane & 15, quad = lane >> 4;

    f32x4 acc[4][4] = {};

    const unsigned short* gA[4];
    const unsigned short* gB[4];
    unsigned short* lA[4];
    unsigned short* lB[4];
    #pragma unroll
    for (int j = 0; j < 4; ++j) {
        int rt = w + (j >> 1) * 4, kblk = j & 1;
        int f = rt * 2 + kblk;
        gA[j] = X + (size_t)(m0 + rt * 16 + l15) * 1024 + kblk * 32 + quad * 8;
        gB[j] = W + (size_t)(n0 + rt * 16 + l15) * 1024 + kblk * 32 + quad * 8;
        lA[j] = &As[f * 512 + lane * 8];
        lB[j] = &Bs[f * 512 + lane * 8];
    }
    const unsigned short* frA = &As[(wm * 4) * 1024 + lane * 8];
    const unsigned short* frB = &Bs[(wn * 4) * 1024 + lane * 8];

    for (int k0 = 0; k0 < 1024; k0 += 64) {
        __syncthreads();
        #pragma unroll
        for (int j = 0; j < 4; ++j) {
            gl_lds16(gA[j] + k0, lA[j]);
            gl_lds16(gB[j] + k0, lB[j]);
        }
        __syncthreads();

        #pragma unroll
        for (int kblk = 0; kblk < 2; ++kblk) {
            bf16x8 af[4], bf[4];
            #pragma unroll
            for (int mt = 0; mt < 4; ++mt)
                af[mt] = *(const bf16x8*)(frA + mt * 1024 + kblk * 512);
            #pragma unroll
            for (int nt = 0; nt < 4; ++nt)
                bf[nt] = *(const bf16x8*)(frB + nt * 1024 + kblk * 512);
            #pragma unroll
            for (int mt = 0; mt < 4; ++mt)
                #pragma unroll
                for (int nt = 0; nt < 4; ++nt)
                    acc[mt][nt] = __builtin_amdgcn_mfma_f32_16x16x32_bf16(
                        af[mt], bf[nt], acc[mt][nt], 0, 0, 0);
        }
    }

    float bvv[4];
    #pragma unroll
    for (int nt = 0; nt < 4; ++nt)
        bvv[nt] = bias[n0 + wn * 64 + nt * 16 + l15] * bscale;

    #pragma unroll
    for (int mt = 0; mt < 4; ++mt) {
        #pragma unroll
        for (int r = 0; r < 4; ++r) {
            int row = m0 + wm * 64 + mt * 16 + quad * 4 + r;
            unsigned short* yp = Y + (size_t)row * 1024 + n0 + wn * 64;
            #pragma unroll
            for (int nt = 0; nt < 4; ++nt)
                yp[nt * 16 + l15] = f2b(acc[mt][nt][r] + bvv[nt]);
        }
    }
}

// ---------------------------------------------------------------------------
// V transpose: Vb[b*2048+tok][h*64+d] -> Vt[((b*16+h)*64+d)][tok]
// ---------------------------------------------------------------------------
__global__ __launch_bounds__(256) void transpose_v(
    const unsigned short* __restrict__ Vb, unsigned short* __restrict__ Vt)
{
    __shared__ unsigned short L[64 * 72];
    const int t0 = blockIdx.x * 64, h = blockIdx.y, b = blockIdx.z;
    const int rr = threadIdx.x >> 3;
    const int cc = (threadIdx.x & 7) * 8;

    #pragma unroll
    for (int p = 0; p < 2; ++p) {
        int r = rr + p * 32;
        *(bf16x8*)(&L[r * 72 + cc]) =
            *(const bf16x8*)(Vb + (size_t)(b * 2048 + t0 + r) * 1024 + h * 64 + cc);
    }
    __syncthreads();
    #pragma unroll
    for (int p = 0; p < 2; ++p) {
        int d = rr + p * 32;
        bf16x8 v;
        #pragma unroll
        for (int j = 0; j < 8; ++j)
            v[j] = (short)L[(cc + j) * 72 + d];
        *(bf16x8*)(Vt + ((size_t)(b * 16 + h) * 64 + d) * 2048 + t0 + cc) = v;
    }
}

// ---------------------------------------------------------------------------
// Flash attention v6. Grid (8,16,4) = 512 blocks (2/CU), block 256 (4 waves).
// 256 q/block = 64 q/wave (4 halves of 16). 128-key staged tiles, computed
// in two 64-key chunks. K/V fragments read from LDS ONCE per chunk and
// reused across all 4 query-halves (LDS-BW was the r5/r6 bottleneck:
// ~10 B/score -> 6 B/score). No-max softmax (Q pre-scaled by 0.125*log2e),
// p=exp2(s), row-sums via all-ones-B MFMA, normalize once at end.
// LDS: Ks 16K + Vs 16K + Ps 32K = 64KB -> 2 blocks/CU.
// ---------------------------------------------------------------------------
__global__ __launch_bounds__(256, 2) void attn_kernel(
    const unsigned short* __restrict__ Q,
    const unsigned short* __restrict__ Kp,
    const unsigned short* __restrict__ Vt,
    float* __restrict__ Out)
{
    __shared__ unsigned short Ks[16 * 512];   // frag f=kt*2+dblk: K[kt*16+l15][dblk*32+quad*8+j]
    __shared__ unsigned short Vs[16 * 512];   // frag f=nt*4+hb:  V^T[nt*16+l15][hb*32+quad*8+j]
    __shared__ unsigned short Ps[4][4096];    // per-wave, per-half 1024: P[16q][64k] frag-ordered

    const int tid  = threadIdx.x;
    const int lane = tid & 63;
    const int w    = tid >> 6;
    const int l15  = lane & 15, quad = lane >> 4;
    const int b = blockIdx.z, h = blockIdx.y, qt = blockIdx.x;

    bf16x8 qf[4][2];
    #pragma unroll
    for (int half = 0; half < 4; ++half) {
        const unsigned short* qptr =
            Q + (size_t)(b * LQ_ + qt * 256 + w * 64 + half * 16 + l15) * 1024 + h * 64;
        qf[half][0] = *(const bf16x8*)(qptr + quad * 8);
        qf[half][1] = *(const bf16x8*)(qptr + 32 + quad * 8);
    }

    bf16x8 ones;
    #pragma unroll
    for (int j = 0; j < 8; ++j) ones[j] = (short)0x3F80;   // bf16 1.0

    f32x4 oacc[4][4] = {};
    f32x4 lacc[4]    = {};

    const unsigned short* Kbase = Kp + (size_t)b * LK_ * 1024 + h * 64;
    const unsigned short* Vbase = Vt + (size_t)(b * 16 + h) * 64 * 2048;

    const unsigned short* gK[4];
    unsigned short* lK[4];
    const unsigned short* gV[4];
    unsigned short* lV[4];
    #pragma unroll
    for (int j = 0; j < 4; ++j) {
        int kt = w + (j >> 1) * 4, dblk = j & 1;
        gK[j] = Kbase + (size_t)(kt * 16 + l15) * 1024 + dblk * 32 + quad * 8;
        lK[j] = &Ks[(kt * 2 + dblk) * 512 + lane * 8];
        gV[j] = Vbase + (size_t)(w * 16 + l15) * 2048 + j * 32 + quad * 8;
        lV[j] = &Vs[(w * 4 + j) * 512 + lane * 8];
    }

    // P region: element (q,k) at half*1024 + (k>>3)*128 + q*8 + (k&7)
    const int pws = (quad >> 1) * 128 + l15 * 8 + (quad & 1) * 4;
    unsigned short* PwB = &Ps[w][pws];           // + half*1024 + t*256
    const unsigned short* PrB = &Ps[w][lane * 8]; // + half*1024 + hbl*512
    const unsigned short* Kfr = &Ks[lane * 8];
    const unsigned short* Vfr = &Vs[lane * 8];

    for (int k0 = 0; k0 < LK_; k0 += 128) {
        __syncthreads();
        #pragma unroll
        for (int j = 0; j < 4; ++j) {
            gl_lds16(gK[j] + (size_t)k0 * 1024, lK[j]);
            gl_lds16(gV[j] + k0, lV[j]);
        }
        __syncthreads();

        #pragma unroll
        for (int cc = 0; cc < 2; ++cc) {          // two 64-key chunks
            // ---- QK^T, all 4 halves share each kf read ----
            f32x4 st[4][4] = {};
            #pragma unroll
            for (int t = 0; t < 4; ++t)
                #pragma unroll
                for (int dblk = 0; dblk < 2; ++dblk) {
                    bf16x8 kf = *(const bf16x8*)(Kfr + ((cc * 4 + t) * 2 + dblk) * 512);
                    #pragma unroll
                    for (int half = 0; half < 4; ++half)
                        st[half][t] = __builtin_amdgcn_mfma_f32_16x16x32_bf16(
                            kf, qf[half][dblk], st[half][t], 0, 0, 0);
                }

            // ---- p = exp2(s); pack (RHU) into per-half P regions ----
            #pragma unroll
            for (int half = 0; half < 4; ++half) {
                unsigned short* pw = PwB + half * 1024;
                #pragma unroll
                for (int t = 0; t < 4; ++t) {
                    unsigned u0 = __float_as_uint(EXP2F(st[half][t][0])) + 0x8000u;
                    unsigned u1 = __float_as_uint(EXP2F(st[half][t][1])) + 0x8000u;
                    unsigned u2 = __float_as_uint(EXP2F(st[half][t][2])) + 0x8000u;
                    unsigned u3 = __float_as_uint(EXP2F(st[half][t][3])) + 0x8000u;
                    uint2 pk;
                    pk.x = __builtin_amdgcn_perm(u1, u0, 0x07060302);
                    pk.y = __builtin_amdgcn_perm(u3, u2, 0x07060302);
                    *(uint2*)(pw + t * 256) = pk;
                }
            }

            // ---- PV + ones row-sum; vf read once per (nt,hbl), shared by halves ----
            #pragma unroll
            for (int hbl = 0; hbl < 2; ++hbl) {
                bf16x8 pf[4];
                #pragma unroll
                for (int half = 0; half < 4; ++half) {
                    pf[half] = *(const bf16x8*)(PrB + half * 1024 + hbl * 512);
                    lacc[half] = __builtin_amdgcn_mfma_f32_16x16x32_bf16(
                        pf[half], ones, lacc[half], 0, 0, 0);
                }
                int hb = cc * 2 + hbl;
                #pragma unroll
                for (int nt = 0; nt < 4; ++nt) {
                    bf16x8 vf = *(const bf16x8*)(Vfr + (nt * 4 + hb) * 512);
                    #pragma unroll
                    for (int half = 0; half < 4; ++half)
                        oacc[half][nt] = __builtin_amdgcn_mfma_f32_16x16x32_bf16(
                            pf[half], vf, oacc[half][nt], 0, 0, 0);
                }
            }
        }
    }

    // ---- normalize + store ----
    #pragma unroll
    for (int half = 0; half < 4; ++half) {
        float il[4];
        #pragma unroll
        for (int r = 0; r < 4; ++r) il[r] = 1.0f / lacc[half][r];
        #pragma unroll
        for (int nt = 0; nt < 4; ++nt) {
            #pragma unroll
            for (int r = 0; r < 4; ++r) {
                size_t orow = (size_t)(b * LQ_ + qt * 256 + w * 64 + half * 16 + quad * 4 + r);
                Out[orow * 1024 + h * 64 + nt * 16 + l15] = oacc[half][nt][r] * il[r];
            }
        }
    }
}

// ---------------------------------------------------------------------------
extern "C" void kernel_launch(void* const* d_in, const int* in_sizes, int n_in,
                              void* d_out, int out_size, void* d_ws, size_t ws_size,
                              hipStream_t stream) {
    const float* zt = (const float*)d_in[0];
    const float* ic = (const float*)d_in[1];
    const float* Wq = (const float*)d_in[2];
    const float* bq = (const float*)d_in[3];
    const float* Wk = (const float*)d_in[4];
    const float* bk = (const float*)d_in[5];
    const float* Wv = (const float*)d_in[6];
    const float* bv = (const float*)d_in[7];
    float* out = (float*)d_out;

    const size_t M8 = (size_t)8192 * 1024;
    const size_t M1 = (size_t)1024 * 1024;
    unsigned short* Qb  = (unsigned short*)d_ws;
    unsigned short* Kb  = Qb  + M8;
    unsigned short* Vb  = Kb  + M8;
    unsigned short* Xz  = Vb  + M8;
    unsigned short* Xi  = Xz  + M8;
    unsigned short* Wqb = Xi  + M8;
    unsigned short* Wkb = Wqb + M1;
    unsigned short* Wvb = Wkb + M1;
    unsigned short* Vtb = Xz;                // Xz dead after qkv_gemm

    const float qscale = 0.125f * 1.44269504088896f;  // 1/sqrt(64) * log2(e)

    dim3 gcv(4096, 5);
    cvt_all<<<gcv, 256, 0, stream>>>(zt, Xz, ic, Xi,
                                     Wq, Wqb, qscale, Wk, Wkb, Wv, Wvb,
                                     (int)M8, (int)M1);

    dim3 gproj(24, 64);                      // (proj*8 + ntile), M/128
    qkv_gemm<<<gproj, 256, 0, stream>>>(Xz, Xi, Wqb, Wkb, Wvb,
                                        bq, bk, bv, qscale, Qb, Kb, Vb);

    dim3 gtr(32, 16, 4);
    transpose_v<<<gtr, 256, 0, stream>>>(Vb, Vtb);

    dim3 gattn(8, 16, 4);                    // LQ/256, H, B
    attn_kernel<<<gattn, 256, 0, stream>>>(Qb, Kb, Vtb, out);
}